// Round 10
// baseline (185.751 us; speedup 1.0000x reference)
//
#include <hip/hip_runtime.h>

#define N_NODES 4096
#define IN_FEAT 128
#define OUT_FEAT 64
#define NHEAD 4
#define HID 256           // NHEAD * OUT_FEAT
#define NEG_SLOPE 0.2f
#define MAXC 256          // per-node neighbor cap (expected max degree ~75)
#define GEMM_BLOCKS 256   // 64 row-blocks x 4 col-blocks (64x64 output tiles)

typedef float f4 __attribute__((ext_vector_type(4)));

static __device__ __forceinline__ unsigned short f2bf(float f) {
    unsigned b = __float_as_uint(f);
    return (unsigned short)((b + 0x7FFFu + ((b >> 16) & 1u)) >> 16);   // RNE
}
static __device__ __forceinline__ float bf2f(unsigned short s) {
    return __uint_as_float(((unsigned)s) << 16);
}

// ---------------------------------------------------------------------------
// Single fused kernel.
//  blocks 0..255    : register-tiled GEMM h=x@W (64x64 tile, 4x4/thread) +
//                     fused attn_src/tgt reductions (bf16 h). On completion
//                     each block fences + atomicAdd(gate).
//  blocks 256..4351 : node i = blockIdx-256. Scan adj row -> LDS neighbor
//                     list (no global list traffic), spin-gate until GEMM
//                     done (~3us, hidden under scan), then no-max softmax +
//                     bf16 aggregation, write out. Dispatch order guarantees
//                     GEMM blocks are resident first -> gate is deadlock-free.
// ---------------------------------------------------------------------------
__global__ __launch_bounds__(256) void k_fused(
    const float* __restrict__ x, const float* __restrict__ adj,
    const float* __restrict__ W, const float* __restrict__ a,
    unsigned short* __restrict__ h_bf, float* __restrict__ attn_src,
    float* __restrict__ attn_tgt, int* __restrict__ gate,
    float* __restrict__ out)
{
    __shared__ f4 xs4[64][32];        // x tile, XOR-swizzled along kq (32KB)
    __shared__ float red_s[4][64];
    __shared__ float red_t[4][64];
    __shared__ int wsum[4];
    __shared__ unsigned short nl[MAXC];
    __shared__ float p[NHEAD][MAXC];

    const int t = threadIdx.x;

    if (blockIdx.x < GEMM_BLOCKS) {
        const int rb = blockIdx.x >> 2;        // row block 0..63
        const int cb = blockIdx.x & 3;         // col block == head
        const int row0 = rb * 64;
        const int tc4 = (t >> 4) * 4;
        const int c0 = cb * 64 + tc4;
        const int tr = t & 15;
        const int wv = t >> 6;

        {
            const f4* xg = reinterpret_cast<const f4*>(x) + (size_t)row0 * 32;
            const int kq = t & 31;
            #pragma unroll
            for (int it = 0; it < 8; ++it) {
                const int r = it * 8 + (t >> 5);
                xs4[r][kq ^ ((r >> 2) & 7)] = xg[r * 32 + kq];
            }
        }
        __syncthreads();

        f4 acc[4] = {};
        for (int kq = 0; kq < 32; ++kq) {
            f4 wvv[4];
            #pragma unroll
            for (int kk = 0; kk < 4; ++kk)
                wvv[kk] = *reinterpret_cast<const f4*>(W + (kq * 4 + kk) * HID + c0);
            f4 xv[4];
            #pragma unroll
            for (int j = 0; j < 4; ++j)
                xv[j] = xs4[tr * 4 + j][kq ^ (tr & 7)];
            #pragma unroll
            for (int kk = 0; kk < 4; ++kk)
                #pragma unroll
                for (int j = 0; j < 4; ++j)
                    acc[j] += xv[j][kk] * wvv[kk];
        }

        // ---- write h (bf16) ----
        #pragma unroll
        for (int j = 0; j < 4; ++j) {
            const int row = row0 + tr * 4 + j;
            ushort4 hb;
            hb.x = f2bf(acc[j][0]); hb.y = f2bf(acc[j][1]);
            hb.z = f2bf(acc[j][2]); hb.w = f2bf(acc[j][3]);
            *reinterpret_cast<ushort4*>(h_bf + (size_t)row * HID + c0) = hb;
        }

        const f4 asv = *reinterpret_cast<const f4*>(a + cb * 2 * OUT_FEAT + tc4);
        const f4 atv = *reinterpret_cast<const f4*>(a + cb * 2 * OUT_FEAT + OUT_FEAT + tc4);
        #pragma unroll
        for (int j = 0; j < 4; ++j) {
            float s = acc[j][0] * asv[0] + acc[j][1] * asv[1]
                    + acc[j][2] * asv[2] + acc[j][3] * asv[3];
            float g = acc[j][0] * atv[0] + acc[j][1] * atv[1]
                    + acc[j][2] * atv[2] + acc[j][3] * atv[3];
            s += __shfl_xor(s, 16, 64); s += __shfl_xor(s, 32, 64);
            g += __shfl_xor(g, 16, 64); g += __shfl_xor(g, 32, 64);
            if (((t >> 4) & 3) == 0) {
                red_s[wv][tr * 4 + j] = s;
                red_t[wv][tr * 4 + j] = g;
            }
        }
        __syncthreads();
        if (t < 64) {
            const float s = red_s[0][t] + red_s[1][t] + red_s[2][t] + red_s[3][t];
            const float g = red_t[0][t] + red_t[1][t] + red_t[2][t] + red_t[3][t];
            attn_src[(row0 + t) * NHEAD + cb] = s;
            attn_tgt[(row0 + t) * NHEAD + cb] = g;
        }
        // ---- completion signal (canonical bar + fence + atomic) ----
        __syncthreads();
        if (t == 0) {
            __threadfence();
            atomicAdd(gate, 1);
        }
    } else {
        // ---- scan adj row -> LDS list, gate, softmax + agg ----
        const int i = blockIdx.x - GEMM_BLOCKS;
        const int lane = t & 63;
        const int wv = t >> 6;
        const int head = wv;

        nl[t] = 0;                                  // pad for agg loop

        const float4* arow = reinterpret_cast<const float4*>(adj + (size_t)i * N_NODES);
        unsigned mask16 = 0;
        #pragma unroll
        for (int u = 0; u < 4; ++u) {
            float4 v = arow[u * 256 + t];
            int jb = u * 1024 + t * 4;
            if (v.x != 0.f || (jb + 0) == i) mask16 |= 1u << (u * 4 + 0);
            if (v.y != 0.f || (jb + 1) == i) mask16 |= 1u << (u * 4 + 1);
            if (v.z != 0.f || (jb + 2) == i) mask16 |= 1u << (u * 4 + 2);
            if (v.w != 0.f || (jb + 3) == i) mask16 |= 1u << (u * 4 + 3);
        }
        int cnt = __popc(mask16);

        int incl = cnt;
        #pragma unroll
        for (int d2 = 1; d2 < 64; d2 <<= 1) {
            int u2 = __shfl_up(incl, d2, 64);
            if (lane >= d2) incl += u2;
        }
        if (lane == 63) wsum[wv] = incl;
        __syncthreads();                            // covers nl zeroing + wsum
        int base = 0;
        #pragma unroll
        for (int w = 0; w < 4; ++w) base += (w < wv) ? wsum[w] : 0;
        int total = wsum[0] + wsum[1] + wsum[2] + wsum[3];
        if (total > MAXC) total = MAXC;
        int off = base + incl - cnt;

        unsigned m = mask16;
        while (m) {
            int b = __ffs((int)m) - 1;
            m &= m - 1;
            int j = ((b >> 2) * 1024) + t * 4 + (b & 3);
            if (off < MAXC) nl[off] = (unsigned short)j;
            ++off;
        }

        // ---- wait for GEMM completion (h, attn_src/tgt visible) ----
        if (t == 0) {
            while (__hip_atomic_load(gate, __ATOMIC_ACQUIRE,
                                     __HIP_MEMORY_SCOPE_AGENT) < GEMM_BLOCKS)
                __builtin_amdgcn_s_sleep(2);
        }
        __syncthreads();                            // covers scatter + gate
        const int d = total;

        // ---- no-max single-pass softmax (|e| small; exact softmax) ----
        const float srcv = attn_src[i * NHEAD + head];
        const int rnd = (d + 3) & ~3;
        float ssum = 0.f;
        for (int idx = lane; idx < rnd; idx += 64) {
            if (idx < d) {
                float e = srcv + attn_tgt[nl[idx] * NHEAD + head];
                e = (e > 0.f) ? e : NEG_SLOPE * e;
                float pe = __expf(e);
                p[head][idx] = pe;
                ssum += pe;
            } else {
                p[head][idx] = 0.f;
            }
        }
        #pragma unroll
        for (int s = 32; s; s >>= 1) ssum += __shfl_xor(ssum, s, 64);
        const float inv = 1.0f / ssum;              // d >= 1 (self loop)

        // ---- aggregation: 4 neighbors/iter, bf16 h gathers ----
        const int g  = lane >> 4;
        const int f4i = lane & 15;
        const unsigned short* hbase = h_bf + head * OUT_FEAT + f4i * 4;
        float4 acc = {0.f, 0.f, 0.f, 0.f};
        for (int idx4 = 0; idx4 < d; idx4 += 4) {
            const int j   = nl[idx4 + g];
            const float pw = p[head][idx4 + g];
            const ushort4 hv = *reinterpret_cast<const ushort4*>(hbase + (size_t)j * HID);
            acc.x += pw * bf2f(hv.x); acc.y += pw * bf2f(hv.y);
            acc.z += pw * bf2f(hv.z); acc.w += pw * bf2f(hv.w);
        }
        #pragma unroll
        for (int s = 16; s <= 32; s <<= 1) {
            acc.x += __shfl_xor(acc.x, s, 64);
            acc.y += __shfl_xor(acc.y, s, 64);
            acc.z += __shfl_xor(acc.z, s, 64);
            acc.w += __shfl_xor(acc.w, s, 64);
        }
        if (g == 0) {
            float4 o = {acc.x * inv, acc.y * inv, acc.z * inv, acc.w * inv};
            *reinterpret_cast<float4*>(out + (size_t)i * HID + head * OUT_FEAT + f4i * 4) = o;
        }
    }
}

// ---------------------------------------------------------------------------
extern "C" void kernel_launch(void* const* d_in, const int* in_sizes, int n_in,
                              void* d_out, int out_size, void* d_ws, size_t ws_size,
                              hipStream_t stream)
{
    const float* x   = (const float*)d_in[0];   // (4096,128)
    const float* adj = (const float*)d_in[1];   // (4096,4096)
    const float* W   = (const float*)d_in[2];   // (128,256)
    const float* a   = (const float*)d_in[3];   // (4,128)
    float* out = (float*)d_out;                 // (4096,256)

    char* ws = (char*)d_ws;
    unsigned short* h_bf = (unsigned short*)ws;                       // 2 MB
    float* attn_src  = (float*)(ws + (size_t)N_NODES * HID * 2);      // 64 KB
    float* attn_tgt  = attn_src + (size_t)N_NODES * NHEAD;            // 64 KB
    int* gate        = (int*)(attn_tgt + (size_t)N_NODES * NHEAD);    // 4 B

    hipMemsetAsync(gate, 0, sizeof(int), stream);
    k_fused<<<GEMM_BLOCKS + N_NODES, 256, 0, stream>>>(
        x, adj, W, a, h_bf, attn_src, attn_tgt, gate, out);
}

// Round 11
// 31.355 us; speedup vs baseline: 5.9242x; 5.9242x over previous
//
#include <hip/hip_runtime.h>

#define N_NODES 4096
#define IN_FEAT 128
#define OUT_FEAT 64
#define NHEAD 4
#define HID 256           // NHEAD * OUT_FEAT
#define NEG_SLOPE 0.2f
#define MAXC 256          // per-node neighbor cap (expected max degree ~75)
#define GEMM_BLOCKS 256   // 64 row-blocks x 4 col-blocks (64x64 output tiles)

typedef float f4 __attribute__((ext_vector_type(4)));

static __device__ __forceinline__ unsigned short f2bf(float f) {
    unsigned b = __float_as_uint(f);
    return (unsigned short)((b + 0x7FFFu + ((b >> 16) & 1u)) >> 16);   // RNE
}
static __device__ __forceinline__ float bf2f(unsigned short s) {
    return __uint_as_float(((unsigned)s) << 16);
}

// ---------------------------------------------------------------------------
// Kernel 1 (heterogeneous, round-3 structure): blocks 0..255 = register-tiled
// GEMM (64x64 tile, 4x4/thread) + fused attn reductions, h stored BF16;
// blocks 256..4351 = block-per-row adj scan -> compacted u16 neighbor lists.
// ---------------------------------------------------------------------------
__global__ __launch_bounds__(256) void k_prep(
    const float* __restrict__ x, const float* __restrict__ adj,
    const float* __restrict__ W, const float* __restrict__ a,
    unsigned short* __restrict__ h_bf, float* __restrict__ attn_src,
    float* __restrict__ attn_tgt,
    unsigned short* __restrict__ nbrs, int* __restrict__ deg)
{
    __shared__ f4 xs4[64][32];        // x tile, XOR-swizzled along kq (32KB)
    __shared__ float red_s[4][64];
    __shared__ float red_t[4][64];
    __shared__ int wsum[4];

    const int t = threadIdx.x;

    if (blockIdx.x < GEMM_BLOCKS) {
        const int rb = blockIdx.x >> 2;        // row block 0..63
        const int cb = blockIdx.x & 3;         // col block == head
        const int row0 = rb * 64;
        const int tc4 = (t >> 4) * 4;
        const int c0 = cb * 64 + tc4;
        const int tr = t & 15;
        const int wv = t >> 6;

        {
            const f4* xg = reinterpret_cast<const f4*>(x) + (size_t)row0 * 32;
            const int kq = t & 31;
            #pragma unroll
            for (int it = 0; it < 8; ++it) {
                const int r = it * 8 + (t >> 5);
                xs4[r][kq ^ ((r >> 2) & 7)] = xg[r * 32 + kq];
            }
        }
        __syncthreads();

        f4 acc[4] = {};
        for (int kq = 0; kq < 32; ++kq) {
            f4 wvv[4];
            #pragma unroll
            for (int kk = 0; kk < 4; ++kk)
                wvv[kk] = *reinterpret_cast<const f4*>(W + (kq * 4 + kk) * HID + c0);
            f4 xv[4];
            #pragma unroll
            for (int j = 0; j < 4; ++j)
                xv[j] = xs4[tr * 4 + j][kq ^ (tr & 7)];
            #pragma unroll
            for (int kk = 0; kk < 4; ++kk)
                #pragma unroll
                for (int j = 0; j < 4; ++j)
                    acc[j] += xv[j][kk] * wvv[kk];
        }

        // ---- write h (bf16, ushort4 = 8B per thread-row) ----
        #pragma unroll
        for (int j = 0; j < 4; ++j) {
            const int row = row0 + tr * 4 + j;
            ushort4 hb;
            hb.x = f2bf(acc[j][0]); hb.y = f2bf(acc[j][1]);
            hb.z = f2bf(acc[j][2]); hb.w = f2bf(acc[j][3]);
            *reinterpret_cast<ushort4*>(h_bf + (size_t)row * HID + c0) = hb;
        }

        const f4 asv = *reinterpret_cast<const f4*>(a + cb * 2 * OUT_FEAT + tc4);
        const f4 atv = *reinterpret_cast<const f4*>(a + cb * 2 * OUT_FEAT + OUT_FEAT + tc4);
        #pragma unroll
        for (int j = 0; j < 4; ++j) {
            float s = acc[j][0] * asv[0] + acc[j][1] * asv[1]
                    + acc[j][2] * asv[2] + acc[j][3] * asv[3];
            float g = acc[j][0] * atv[0] + acc[j][1] * atv[1]
                    + acc[j][2] * atv[2] + acc[j][3] * atv[3];
            s += __shfl_xor(s, 16, 64); s += __shfl_xor(s, 32, 64);
            g += __shfl_xor(g, 16, 64); g += __shfl_xor(g, 32, 64);
            if (((t >> 4) & 3) == 0) {
                red_s[wv][tr * 4 + j] = s;
                red_t[wv][tr * 4 + j] = g;
            }
        }
        __syncthreads();
        if (t < 64) {
            const float s = red_s[0][t] + red_s[1][t] + red_s[2][t] + red_s[3][t];
            const float g = red_t[0][t] + red_t[1][t] + red_t[2][t] + red_t[3][t];
            attn_src[(row0 + t) * NHEAD + cb] = s;
            attn_tgt[(row0 + t) * NHEAD + cb] = g;
        }
    } else {
        // ---- adj scan: block-per-row (round-3 verbatim) ----
        const int i = blockIdx.x - GEMM_BLOCKS;
        const int lane = t & 63;
        const int wv = t >> 6;

        const float4* arow = reinterpret_cast<const float4*>(adj + (size_t)i * N_NODES);
        unsigned mask16 = 0;
        #pragma unroll
        for (int u = 0; u < 4; ++u) {
            float4 v = arow[u * 256 + t];
            int jb = u * 1024 + t * 4;
            if (v.x != 0.f || (jb + 0) == i) mask16 |= 1u << (u * 4 + 0);
            if (v.y != 0.f || (jb + 1) == i) mask16 |= 1u << (u * 4 + 1);
            if (v.z != 0.f || (jb + 2) == i) mask16 |= 1u << (u * 4 + 2);
            if (v.w != 0.f || (jb + 3) == i) mask16 |= 1u << (u * 4 + 3);
        }
        int cnt = __popc(mask16);

        int incl = cnt;
        #pragma unroll
        for (int d = 1; d < 64; d <<= 1) {
            int u2 = __shfl_up(incl, d, 64);
            if (lane >= d) incl += u2;
        }
        if (lane == 63) wsum[wv] = incl;
        __syncthreads();
        int base = 0;
        #pragma unroll
        for (int w = 0; w < 4; ++w) base += (w < wv) ? wsum[w] : 0;
        int total = wsum[0] + wsum[1] + wsum[2] + wsum[3];
        if (total > MAXC) total = MAXC;
        int off = base + incl - cnt;

        unsigned m = mask16;
        unsigned short* nl = nbrs + (size_t)i * MAXC;
        while (m) {
            int b = __ffs((int)m) - 1;
            m &= m - 1;
            int j = ((b >> 2) * 1024) + t * 4 + (b & 3);
            if (off < MAXC) nl[off] = (unsigned short)j;
            ++off;
        }
        if (t == 0) deg[i] = total;
    }
}

// ---------------------------------------------------------------------------
// Kernel 2: per node i — NO-MAX single-pass softmax (|e|<~8 so exp is f32-safe
// without max subtraction; softmax identical) + bf16 aggregation.
// Wave wv owns head wv; 4 neighbors/iter in the agg loop.
// ---------------------------------------------------------------------------
__global__ __launch_bounds__(256) void k_agg(
    const unsigned short* __restrict__ nbrs, const int* __restrict__ deg,
    const unsigned short* __restrict__ h_bf, const float* __restrict__ attn_src,
    const float* __restrict__ attn_tgt, float* __restrict__ out)
{
    __shared__ float p[NHEAD][MAXC];
    __shared__ unsigned short nl[MAXC];

    const int i = blockIdx.x;
    const int t = threadIdx.x;
    const int lane = t & 63;
    const int head = t >> 6;

    const int d = deg[i];
    nl[t] = (t < d) ? nbrs[(size_t)i * MAXC + t] : (unsigned short)0;
    __syncthreads();

    // ---- single-pass: p = exp(LeakyReLU(src+tgt)), running sum ----
    const float srcv = attn_src[i * NHEAD + head];
    const int rnd = (d + 3) & ~3;
    float ssum = 0.f;
    for (int idx = lane; idx < rnd; idx += 64) {
        if (idx < d) {
            float e = srcv + attn_tgt[nl[idx] * NHEAD + head];
            e = (e > 0.f) ? e : NEG_SLOPE * e;
            float pe = __expf(e);
            p[head][idx] = pe;
            ssum += pe;
        } else {
            p[head][idx] = 0.f;   // padding consumed with weight 0 below
        }
    }
    #pragma unroll
    for (int s = 32; s; s >>= 1) ssum += __shfl_xor(ssum, s, 64);
    const float inv = 1.0f / ssum;   // d >= 1 always (self loop)

    // ---- aggregation: 4 neighbors per iteration, bf16 h gathers ----
    const int g  = lane >> 4;        // neighbor sub-slot 0..3
    const int f4i = lane & 15;       // feature chunk 0..15 (4 feats each)
    const unsigned short* hbase = h_bf + head * OUT_FEAT + f4i * 4;
    float4 acc = {0.f, 0.f, 0.f, 0.f};
    for (int idx4 = 0; idx4 < d; idx4 += 4) {
        const int j   = nl[idx4 + g];          // LDS broadcast (pad -> 0)
        const float pw = p[head][idx4 + g];    // pad -> 0
        const ushort4 hv = *reinterpret_cast<const ushort4*>(hbase + (size_t)j * HID);
        acc.x += pw * bf2f(hv.x); acc.y += pw * bf2f(hv.y);
        acc.z += pw * bf2f(hv.z); acc.w += pw * bf2f(hv.w);
    }
    #pragma unroll
    for (int s = 16; s <= 32; s <<= 1) {
        acc.x += __shfl_xor(acc.x, s, 64);
        acc.y += __shfl_xor(acc.y, s, 64);
        acc.z += __shfl_xor(acc.z, s, 64);
        acc.w += __shfl_xor(acc.w, s, 64);
    }
    if (g == 0) {
        float4 o = {acc.x * inv, acc.y * inv, acc.z * inv, acc.w * inv};
        *reinterpret_cast<float4*>(out + (size_t)i * HID + head * OUT_FEAT + f4i * 4) = o;
    }
}

// ---------------------------------------------------------------------------
extern "C" void kernel_launch(void* const* d_in, const int* in_sizes, int n_in,
                              void* d_out, int out_size, void* d_ws, size_t ws_size,
                              hipStream_t stream)
{
    const float* x   = (const float*)d_in[0];   // (4096,128)
    const float* adj = (const float*)d_in[1];   // (4096,4096)
    const float* W   = (const float*)d_in[2];   // (128,256)
    const float* a   = (const float*)d_in[3];   // (4,128)
    float* out = (float*)d_out;                 // (4096,256)

    char* ws = (char*)d_ws;
    unsigned short* h_bf = (unsigned short*)ws;                       // 2 MB
    float* attn_src  = (float*)(ws + (size_t)N_NODES * HID * 2);      // 64 KB
    float* attn_tgt  = attn_src + (size_t)N_NODES * NHEAD;            // 64 KB
    unsigned short* nbrs = (unsigned short*)(attn_tgt + (size_t)N_NODES * NHEAD); // 2 MB
    int* deg         = (int*)(nbrs + (size_t)N_NODES * MAXC);         // 16 KB

    k_prep<<<GEMM_BLOCKS + N_NODES, 256, 0, stream>>>(
        x, adj, W, a, h_bf, attn_src, attn_tgt, nbrs, deg);
    k_agg<<<N_NODES, 256, 0, stream>>>(nbrs, deg, h_bf, attn_src, attn_tgt, out);
}